// Round 5
// baseline (739.714 us; speedup 1.0000x reference)
//
#include <hip/hip_runtime.h>
#include <hip/hip_bf16.h>
#include <hip/hip_cooperative_groups.h>

namespace cg = cooperative_groups;

#define N_NODES 50000
#define N_EDGES 800000
#define D_IN 128
#define D_HID 512
#define D_OUT 128
#define CAT_DIM 640   // D_IN + D_HID
#define CAP 64        // per-node edge-bucket capacity (Poisson(16): P(>=64) ~ 1e-20)

typedef __attribute__((ext_vector_type(8))) short short8;
typedef __attribute__((ext_vector_type(4))) float floatx4;

__device__ __forceinline__ unsigned short f2bf(float f) {
    unsigned u = __float_as_uint(f);
    unsigned r = u + 0x7fffu + ((u >> 16) & 1u);   // RNE
    return (unsigned short)(r >> 16);
}

// ================= stage work as device functions (shared by mega + fallback) ==============

#define PREP_CASTX_BLOCKS   6250   // 50000*32 threads / 256
#define PREP_FCW_BLOCKS      256   // 128*512 / 256
#define PREP_W2_BLOCKS       320   // 640*128 / 256
#define PREP_DEG_BLOCKS      196   // ceil(50000/256)
#define PREP_TOTAL_BLOCKS  (PREP_CASTX_BLOCKS + PREP_FCW_BLOCKS + PREP_W2_BLOCKS + PREP_DEG_BLOCKS + 1)
#define HIST_VB             1563   // ceil((N_EDGES/2)/256)
#define GEMM1_VB            3128   // 782 M-tiles * 4 N-tiles
#define AGG_VB             12500   // N_NODES / 4
#define GEMM2_VB             782

__device__ __forceinline__ void prep_vb(int b, int tid,
                                        const float* __restrict__ X, const float* __restrict__ fcW,
                                        const float* __restrict__ Wm, const int* __restrict__ adj,
                                        unsigned short* __restrict__ concat,
                                        unsigned short* __restrict__ fcwT,
                                        unsigned short* __restrict__ WT,
                                        int* __restrict__ deg, int* __restrict__ flag) {
    if (b < PREP_CASTX_BLOCKS) {
        int t = b * 256 + tid;                 // 50000*32
        int row = t >> 5;
        int cg2 = (t & 31) * 4;
        float4 v = *(const float4*)(X + (size_t)row * D_IN + cg2);
        unsigned short o[4] = { f2bf(v.x), f2bf(v.y), f2bf(v.z), f2bf(v.w) };
        *(unsigned long long*)(concat + (size_t)row * CAT_DIM + cg2) = *(unsigned long long*)o;
        return;
    }
    b -= PREP_CASTX_BLOCKS;
    if (b < PREP_FCW_BLOCKS) {
        int idx = b * 256 + tid;               // 128*512
        int k = idx >> 9;
        int n = idx & (D_HID - 1);
        fcwT[n * D_IN + k] = f2bf(fcW[idx]);
        return;
    }
    b -= PREP_FCW_BLOCKS;
    if (b < PREP_W2_BLOCKS) {
        int idx = b * 256 + tid;               // 640*128
        int k = idx >> 7;
        int n = idx & (D_OUT - 1);
        WT[n * CAT_DIM + k] = f2bf(Wm[idx]);
        return;
    }
    b -= PREP_W2_BLOCKS;
    if (b < PREP_DEG_BLOCKS) {
        int idx = b * 256 + tid;
        if (idx < N_NODES) deg[idx] = 0;
        return;
    }
    // detect (wave 0 only): int64 high words are all 0 (node ids < 2^31)
    if (tid < 64) {
        int v = adj[2 * tid + 1];
        unsigned long long m = __ballot(v != 0);
        if (tid == 0) *flag = (m == 0ULL) ? 2 : 1;   // 2 => int64 stride
    }
}

__device__ __forceinline__ void hist_edges(const int* __restrict__ adj, int s, int e0,
                                           int* __restrict__ deg, int* __restrict__ edge_list) {
    int src0, src1, trg0, trg1;
    if (s == 2) {   // int64: edges e0,e0+1 -> adj dwords [2e0 .. 2e0+3], coalesced
        int4 vs = *(const int4*)(adj + 2 * (size_t)e0);
        int4 vt = *(const int4*)(adj + 2 * ((size_t)N_EDGES + e0));
        src0 = vs.x; src1 = vs.z;
        trg0 = vt.x; trg1 = vt.z;
    } else {        // int32
        int2 vs = *(const int2*)(adj + e0);
        int2 vt = *(const int2*)(adj + N_EDGES + e0);
        src0 = vs.x; src1 = vs.y;
        trg0 = vt.x; trg1 = vt.y;
    }
    int p0 = atomicAdd(&deg[src0], 1);
    if (p0 < CAP) edge_list[src0 * CAP + p0] = trg0;
    int p1 = atomicAdd(&deg[src1], 1);
    if (p1 < CAP) edge_list[src1 * CAP + p1] = trg1;
}

// ---- bf16 MFMA GEMM tile: BM=64, BN=128, 2x2 waves (32x64 wave tiles) ----
#define SMEM_BYTES 15360   // (64+128) * (32+8) * 2

template<int BIAS_RELU, int OUT_BF16>
__device__ __forceinline__ void gemm_tile(char* smem,
    const unsigned short* __restrict__ A, int lda,
    const unsigned short* __restrict__ Bt, int ldb,
    const float* __restrict__ bias, void* __restrict__ Cout, int ldc,
    int M, int K, int bm, int bn)
{
    constexpr int BK = 32, PAD = 8;
    typedef unsigned short Row[BK + PAD];
    Row* As = (Row*)smem;
    Row* Bs = (Row*)(smem + 64 * (BK + PAD) * 2);
    int tid = threadIdx.x;
    int lane = tid & 63, w = tid >> 6;
    int wm = (w >> 1) * 32, wn = (w & 1) * 64;
    int q = lane >> 4, l16 = lane & 15;
    floatx4 acc[2][4] = {};
    int r0 = tid >> 2;          // 0..63
    int cgp = (tid & 3) * 8;    // 0,8,16,24

    for (int k0 = 0; k0 < K; k0 += BK) {
        {
            int gr = bm + r0;
            uint4 va = make_uint4(0u, 0u, 0u, 0u);
            if (gr < M) va = *(const uint4*)(A + (size_t)gr * lda + k0 + cgp);
            *(uint4*)(&As[r0][cgp]) = va;
        }
        #pragma unroll
        for (int p = 0; p < 2; ++p) {
            int r = r0 + p * 64;
            uint4 vb = *(const uint4*)(Bt + (size_t)(bn + r) * ldb + k0 + cgp);
            *(uint4*)(&Bs[r][cgp]) = vb;
        }
        __syncthreads();
        short8 af[2], bf[4];
        #pragma unroll
        for (int i = 0; i < 2; ++i)
            af[i] = *(const short8*)(&As[wm + i * 16 + l16][q * 8]);
        #pragma unroll
        for (int i = 0; i < 4; ++i)
            bf[i] = *(const short8*)(&Bs[wn + i * 16 + l16][q * 8]);
        #pragma unroll
        for (int mi = 0; mi < 2; ++mi)
            #pragma unroll
            for (int ni = 0; ni < 4; ++ni)
                acc[mi][ni] = __builtin_amdgcn_mfma_f32_16x16x32_bf16(af[mi], bf[ni], acc[mi][ni], 0, 0, 0);
        __syncthreads();
    }

    #pragma unroll
    for (int mi = 0; mi < 2; ++mi) {
        #pragma unroll
        for (int ni = 0; ni < 4; ++ni) {
            #pragma unroll
            for (int r = 0; r < 4; ++r) {
                int row = bm + wm + mi * 16 + q * 4 + r;
                int col = bn + wn + ni * 16 + l16;
                if (row < M) {
                    float v = acc[mi][ni][r];
                    if (BIAS_RELU) v = fmaxf(v + bias[col], 0.0f);
                    if (OUT_BF16) ((unsigned short*)Cout)[(size_t)row * ldc + col] = f2bf(v);
                    else          ((float*)Cout)[(size_t)row * ldc + col] = v;
                }
            }
        }
    }
}

// ---- segment max: wave per node, lane owns 8 of 512 dims ----
__device__ __forceinline__ void fmax_bf16x8(float* acc, const uint4& p) {
    const unsigned* a = (const unsigned*)&p;
    #pragma unroll
    for (int j = 0; j < 4; ++j) {
        unsigned u = a[j];
        acc[2 * j]     = fmaxf(acc[2 * j],     __uint_as_float(u << 16));
        acc[2 * j + 1] = fmaxf(acc[2 * j + 1], __uint_as_float(u & 0xffff0000u));
    }
}

__device__ __forceinline__ void aggregate_node(const unsigned short* __restrict__ F,
                                               const int* __restrict__ deg,
                                               const int* __restrict__ edge_list,
                                               unsigned short* __restrict__ concat,
                                               int gw, int lane) {
    int d = deg[gw];
    d = d < CAP ? d : CAP;
    const int* el = edge_list + gw * CAP;
    float acc[8] = {0.f, 0.f, 0.f, 0.f, 0.f, 0.f, 0.f, 0.f};
    int i = 0;
    for (; i + 2 <= d; i += 2) {
        int t0 = el[i], t1 = el[i + 1];
        uint4 p0 = *(const uint4*)(F + (size_t)t0 * D_HID + lane * 8);
        uint4 p1 = *(const uint4*)(F + (size_t)t1 * D_HID + lane * 8);
        fmax_bf16x8(acc, p0);
        fmax_bf16x8(acc, p1);
    }
    if (i < d) {
        uint4 p0 = *(const uint4*)(F + (size_t)el[i] * D_HID + lane * 8);
        fmax_bf16x8(acc, p0);
    }
    unsigned out[4];
    #pragma unroll
    for (int j = 0; j < 4; ++j) {
        unsigned lo = __float_as_uint(acc[2 * j]) >> 16;          // exact: maxima of bf16 values
        unsigned hi = __float_as_uint(acc[2 * j + 1]) & 0xffff0000u;
        out[j] = lo | hi;
    }
    *(uint4*)(concat + (size_t)gw * CAT_DIM + D_IN + lane * 8) = *(uint4*)out;
}

// ================= cooperative megakernel ==================================

#define MEGA_BLOCKS 512   // 2 blocks/CU guaranteed resident (worst-case VGPR via bounds)

__global__ __launch_bounds__(256, 3)
void mega_kernel(const float* __restrict__ X, const float* __restrict__ fcW,
                 const float* __restrict__ fcb, const float* __restrict__ Wm,
                 const int* __restrict__ adj,
                 unsigned short* __restrict__ concat, unsigned short* __restrict__ F,
                 unsigned short* __restrict__ fcwT, unsigned short* __restrict__ WT,
                 int* __restrict__ deg, int* __restrict__ edge_list,
                 int* __restrict__ flag, float* __restrict__ out) {
    __shared__ char smem[SMEM_BYTES];
    cg::grid_group grid = cg::this_grid();
    const int tid = threadIdx.x;

    // ---- S0: prep ----
    for (int vb = blockIdx.x; vb < PREP_TOTAL_BLOCKS; vb += gridDim.x)
        prep_vb(vb, tid, X, fcW, Wm, adj, concat, fcwT, WT, deg, flag);
    __threadfence();
    grid.sync();

    // ---- S1: hist + GEMM1 interleaved (independent work) ----
    int s = flag[0];
    for (int vb = blockIdx.x; vb < HIST_VB + GEMM1_VB; vb += gridDim.x) {
        if (vb < HIST_VB) {
            int e0 = (vb * 256 + tid) * 2;
            if (e0 < N_EDGES) hist_edges(adj, s, e0, deg, edge_list);
        } else {
            int tile = vb - HIST_VB;
            gemm_tile<1, 1>(smem, concat, CAT_DIM, fcwT, D_IN, fcb, F, D_HID,
                            N_NODES, D_IN, (tile >> 2) * 64, (tile & 3) * 128);
        }
    }
    __threadfence();
    grid.sync();

    // ---- S2: aggregate ----
    {
        int wv = tid >> 6, lane = tid & 63;
        for (int vb = blockIdx.x; vb < AGG_VB; vb += gridDim.x)
            aggregate_node(F, deg, edge_list, concat, vb * 4 + wv, lane);
    }
    __threadfence();
    grid.sync();

    // ---- S3: GEMM2 ----
    for (int vb = blockIdx.x; vb < GEMM2_VB; vb += gridDim.x)
        gemm_tile<0, 0>(smem, concat, CAT_DIM, WT, CAT_DIM, nullptr, out, D_OUT,
                        N_NODES, CAT_DIM, vb * 64, 0);
}

// ================= fallback multi-kernel path ==============================

__global__ void prep_kernel(const float* __restrict__ X, const float* __restrict__ fcW,
                            const float* __restrict__ Wm, const int* __restrict__ adj,
                            unsigned short* __restrict__ concat,
                            unsigned short* __restrict__ fcwT,
                            unsigned short* __restrict__ WT,
                            int* __restrict__ deg, int* __restrict__ flag) {
    prep_vb(blockIdx.x, threadIdx.x, X, fcW, Wm, adj, concat, fcwT, WT, deg, flag);
}

__global__ void hist_kernel(const int* __restrict__ adj, const int* __restrict__ flag,
                            int* __restrict__ deg, int* __restrict__ edge_list) {
    int e0 = (blockIdx.x * blockDim.x + threadIdx.x) * 2;
    if (e0 < N_EDGES) hist_edges(adj, flag[0], e0, deg, edge_list);
}

template<int BIAS_RELU, int OUT_BF16>
__global__ __launch_bounds__(256)
void gemm_kernel(const unsigned short* __restrict__ A, int lda,
                 const unsigned short* __restrict__ Bt, int ldb,
                 const float* __restrict__ bias, void* __restrict__ Cout, int ldc,
                 int M, int K) {
    __shared__ char smem[SMEM_BYTES];
    gemm_tile<BIAS_RELU, OUT_BF16>(smem, A, lda, Bt, ldb, bias, Cout, ldc,
                                   M, K, blockIdx.y * 64, blockIdx.x * 128);
}

__global__ __launch_bounds__(256)
void aggregate_kernel(const unsigned short* __restrict__ F,
                      const int* __restrict__ deg,
                      const int* __restrict__ edge_list,
                      unsigned short* __restrict__ concat) {
    int gw = (blockIdx.x * 256 + threadIdx.x) >> 6;
    if (gw >= N_NODES) return;
    aggregate_node(F, deg, edge_list, concat, gw, threadIdx.x & 63);
}

// ================= host launch =============================================

extern "C" void kernel_launch(void* const* d_in, const int* in_sizes, int n_in,
                              void* d_out, int out_size, void* d_ws, size_t ws_size,
                              hipStream_t stream) {
    const float* X    = (const float*)d_in[0];
    const float* fc_w = (const float*)d_in[1];
    const float* fc_b = (const float*)d_in[2];
    const float* Wm   = (const float*)d_in[3];
    const int*   adj  = (const int*)d_in[4];
    float* outp = (float*)d_out;

    char* ws = (char*)d_ws;
    size_t off = 0;
    auto alloc = [&](size_t bytes) -> void* {
        void* p = ws + off;
        off = (off + bytes + 255) & ~(size_t)255;
        return p;
    };
    unsigned short* concat = (unsigned short*)alloc((size_t)N_NODES * CAT_DIM * 2);
    unsigned short* F      = (unsigned short*)alloc((size_t)N_NODES * D_HID * 2);
    unsigned short* fcwT   = (unsigned short*)alloc((size_t)D_HID * D_IN * 2);
    unsigned short* WT     = (unsigned short*)alloc((size_t)D_OUT * CAT_DIM * 2);
    int* deg       = (int*)alloc((size_t)N_NODES * 4);
    int* edge_list = (int*)alloc((size_t)N_NODES * CAP * 4);
    int* flag      = (int*)alloc(256);

    void* args[] = { &X, &fc_w, &fc_b, &Wm, &adj, &concat, &F, &fcwT, &WT,
                     &deg, &edge_list, &flag, &outp };
    hipError_t err = hipLaunchCooperativeKernel((void*)mega_kernel,
                                                dim3(MEGA_BLOCKS), dim3(256),
                                                args, 0, stream);
    if (err != hipSuccess) {
        // deterministic fallback: Round-4 5-kernel pipeline
        prep_kernel<<<PREP_TOTAL_BLOCKS, 256, 0, stream>>>(X, fc_w, Wm, adj, concat, fcwT, WT, deg, flag);
        hist_kernel<<<HIST_VB, 256, 0, stream>>>(adj, flag, deg, edge_list);
        dim3 g1(4, 782);
        gemm_kernel<1, 1><<<g1, 256, 0, stream>>>(concat, CAT_DIM, fcwT, D_IN, fc_b,
                                                  F, D_HID, N_NODES, D_IN);
        aggregate_kernel<<<(N_NODES * 64 + 255) / 256, 256, 0, stream>>>(F, deg, edge_list, concat);
        dim3 g2(1, 782);
        gemm_kernel<0, 0><<<g2, 256, 0, stream>>>(concat, CAT_DIM, WT, CAT_DIM, nullptr,
                                                  outp, D_OUT, N_NODES, CAT_DIM);
    }
}

// Round 6
// 288.873 us; speedup vs baseline: 2.5607x; 2.5607x over previous
//
#include <hip/hip_runtime.h>
#include <hip/hip_bf16.h>

#define N_NODES 50000
#define N_EDGES 800000
#define D_IN 128
#define D_HID 512
#define D_OUT 128
#define CAT_DIM 640   // D_IN + D_HID
#define CAP 64        // per-node edge-bucket capacity (Poisson(16): P(>=64) ~ 1e-20)

typedef __attribute__((ext_vector_type(8))) short short8;
typedef __attribute__((ext_vector_type(4))) float floatx4;

__device__ __forceinline__ unsigned short f2bf(float f) {
    unsigned u = __float_as_uint(f);
    unsigned r = u + 0x7fffu + ((u >> 16) & 1u);   // RNE
    return (unsigned short)(r >> 16);
}

// ================= prep: casts/transposes/deg-zero/dtype-detect ============

#define PREP_CASTX_BLOCKS   6250   // 50000*32 threads / 256
#define PREP_FCW_BLOCKS      256   // 128*512 / 256
#define PREP_W2_BLOCKS       320   // 640*128 / 256
#define PREP_DEG_BLOCKS      196   // ceil(50000/256)
#define PREP_TOTAL_BLOCKS  (PREP_CASTX_BLOCKS + PREP_FCW_BLOCKS + PREP_W2_BLOCKS + PREP_DEG_BLOCKS + 1)

__global__ void prep_kernel(const float* __restrict__ X, const float* __restrict__ fcW,
                            const float* __restrict__ Wm, const int* __restrict__ adj,
                            unsigned short* __restrict__ concat,
                            unsigned short* __restrict__ fcwT,
                            unsigned short* __restrict__ WT,
                            int* __restrict__ deg, int* __restrict__ flag) {
    int b = blockIdx.x;
    int tid = threadIdx.x;
    if (b < PREP_CASTX_BLOCKS) {
        int t = b * 256 + tid;                 // 50000*32
        int row = t >> 5;
        int cg2 = (t & 31) * 4;
        float4 v = *(const float4*)(X + (size_t)row * D_IN + cg2);
        unsigned short o[4] = { f2bf(v.x), f2bf(v.y), f2bf(v.z), f2bf(v.w) };
        *(unsigned long long*)(concat + (size_t)row * CAT_DIM + cg2) = *(unsigned long long*)o;
        return;
    }
    b -= PREP_CASTX_BLOCKS;
    if (b < PREP_FCW_BLOCKS) {
        int idx = b * 256 + tid;               // 128*512
        int k = idx >> 9;
        int n = idx & (D_HID - 1);
        fcwT[n * D_IN + k] = f2bf(fcW[idx]);
        return;
    }
    b -= PREP_FCW_BLOCKS;
    if (b < PREP_W2_BLOCKS) {
        int idx = b * 256 + tid;               // 640*128
        int k = idx >> 7;
        int n = idx & (D_OUT - 1);
        WT[n * CAT_DIM + k] = f2bf(Wm[idx]);
        return;
    }
    b -= PREP_W2_BLOCKS;
    if (b < PREP_DEG_BLOCKS) {
        int idx = b * 256 + tid;
        if (idx < N_NODES) deg[idx] = 0;
        return;
    }
    // detect (wave 0): int64 high words all zero (node ids < 2^31)
    if (tid < 64) {
        int v = adj[2 * tid + 1];
        unsigned long long m = __ballot(v != 0);
        if (tid == 0) *flag = (m == 0ULL) ? 2 : 1;   // 2 => int64 stride
    }
}

// ================= hist (device fn, used in fused mid kernel) ==============

__device__ __forceinline__ void hist_edges(const int* __restrict__ adj, int s, int e0,
                                           int* __restrict__ deg, int* __restrict__ edge_list) {
    int src0, src1, trg0, trg1;
    if (s == 2) {   // int64: edges e0,e0+1 -> adj dwords [2e0 .. 2e0+3], coalesced
        int4 vs = *(const int4*)(adj + 2 * (size_t)e0);
        int4 vt = *(const int4*)(adj + 2 * ((size_t)N_EDGES + e0));
        src0 = vs.x; src1 = vs.z;
        trg0 = vt.x; trg1 = vt.z;
    } else {        // int32
        int2 vs = *(const int2*)(adj + e0);
        int2 vt = *(const int2*)(adj + N_EDGES + e0);
        src0 = vs.x; src1 = vs.y;
        trg0 = vt.x; trg1 = vt.y;
    }
    int p0 = atomicAdd(&deg[src0], 1);
    if (p0 < CAP) edge_list[src0 * CAP + p0] = trg0;
    int p1 = atomicAdd(&deg[src1], 1);
    if (p1 < CAP) edge_list[src1 * CAP + p1] = trg1;
}

// ================= bf16 MFMA GEMM tile: BM=64, BN=128, BK=64, 2x2 waves ====
// As 64x(64+8), Bs 128x(64+8): 27648 B LDS. Fragment-read bank aliasing is
// 2-way (free). K-loop iterations: K/64 (GEMM1: 2, GEMM2: 10).

#define GPAD 8
#define SM64_BYTES ((64 + 128) * (64 + GPAD) * 2)

template<int BIAS_RELU, int OUT_BF16>
__device__ __forceinline__ void gemm_tile64(char* smem,
    const unsigned short* __restrict__ A, int lda,
    const unsigned short* __restrict__ Bt, int ldb,
    const float* __restrict__ bias, void* __restrict__ Cout, int ldc,
    int M, int K, int bm, int bn)
{
    constexpr int BK = 64;
    typedef unsigned short Row[BK + GPAD];
    Row* As = (Row*)smem;
    Row* Bs = (Row*)(smem + 64 * (BK + GPAD) * 2);
    int tid = threadIdx.x;
    int lane = tid & 63, w = tid >> 6;
    int wm = (w >> 1) * 32, wn = (w & 1) * 64;
    int q = lane >> 4, l16 = lane & 15;
    floatx4 acc[2][4] = {};
    int ra = tid >> 2;            // A row 0..63
    int ca = (tid & 3) * 8;       // A col base; passes +0,+32
    int rb = tid >> 1;            // B row 0..127
    int cb = (tid & 1) * 8;       // B col base; passes +0,+16,+32,+48

    for (int k0 = 0; k0 < K; k0 += BK) {
        {
            int gr = bm + ra;
            const unsigned short* ap = A + (size_t)gr * lda + k0 + ca;
            #pragma unroll
            for (int p = 0; p < 2; ++p) {
                uint4 va = make_uint4(0u, 0u, 0u, 0u);
                if (gr < M) va = *(const uint4*)(ap + p * 32);
                *(uint4*)(&As[ra][ca + p * 32]) = va;
            }
        }
        {
            const unsigned short* bp = Bt + (size_t)(bn + rb) * ldb + k0 + cb;
            #pragma unroll
            for (int p = 0; p < 4; ++p)
                *(uint4*)(&Bs[rb][cb + p * 16]) = *(const uint4*)(bp + p * 16);
        }
        __syncthreads();
        #pragma unroll
        for (int ks = 0; ks < 2; ++ks) {
            short8 af[2], bf[4];
            #pragma unroll
            for (int mi = 0; mi < 2; ++mi)
                af[mi] = *(const short8*)(&As[wm + mi * 16 + l16][ks * 32 + q * 8]);
            #pragma unroll
            for (int ni = 0; ni < 4; ++ni)
                bf[ni] = *(const short8*)(&Bs[wn + ni * 16 + l16][ks * 32 + q * 8]);
            #pragma unroll
            for (int mi = 0; mi < 2; ++mi)
                #pragma unroll
                for (int ni = 0; ni < 4; ++ni)
                    acc[mi][ni] = __builtin_amdgcn_mfma_f32_16x16x32_bf16(af[mi], bf[ni], acc[mi][ni], 0, 0, 0);
        }
        __syncthreads();
    }

    #pragma unroll
    for (int mi = 0; mi < 2; ++mi) {
        #pragma unroll
        for (int ni = 0; ni < 4; ++ni) {
            #pragma unroll
            for (int r = 0; r < 4; ++r) {
                int row = bm + wm + mi * 16 + q * 4 + r;
                int col = bn + wn + ni * 16 + l16;
                if (row < M) {
                    float v = acc[mi][ni][r];
                    if (BIAS_RELU) v = fmaxf(v + bias[col], 0.0f);
                    if (OUT_BF16) ((unsigned short*)Cout)[(size_t)row * ldc + col] = f2bf(v);
                    else          ((float*)Cout)[(size_t)row * ldc + col] = v;
                }
            }
        }
    }
}

// ================= fused mid: hist blocks + GEMM1 blocks ===================

#define HIST_VB     1563   // ceil((N_EDGES/2)/256)
#define GEMM1_MT     782   // ceil(50000/64)
#define GEMM1_TILES (GEMM1_MT * 4)

__global__ __launch_bounds__(256)
void mid_kernel(const int* __restrict__ adj, const int* __restrict__ flag,
                int* __restrict__ deg, int* __restrict__ edge_list,
                const unsigned short* __restrict__ concat,
                const unsigned short* __restrict__ fcwT,
                const float* __restrict__ fcb,
                unsigned short* __restrict__ F) {
    if (blockIdx.x < HIST_VB) {
        int e0 = (blockIdx.x * 256 + threadIdx.x) * 2;
        if (e0 < N_EDGES) hist_edges(adj, flag[0], e0, deg, edge_list);
        return;
    }
    __shared__ char smem[SM64_BYTES];
    int tile = blockIdx.x - HIST_VB;
    gemm_tile64<1, 1>(smem, concat, CAT_DIM, fcwT, D_IN, fcb, F, D_HID,
                      N_NODES, D_IN, (tile >> 2) * 64, (tile & 3) * 128);
}

// ================= aggregate: wave per node (Round-4 form, unchanged) ======

__device__ __forceinline__ void fmax_bf16x8(float* acc, const uint4& p) {
    const unsigned* a = (const unsigned*)&p;
    #pragma unroll
    for (int j = 0; j < 4; ++j) {
        unsigned u = a[j];
        acc[2 * j]     = fmaxf(acc[2 * j],     __uint_as_float(u << 16));
        acc[2 * j + 1] = fmaxf(acc[2 * j + 1], __uint_as_float(u & 0xffff0000u));
    }
}

__global__ __launch_bounds__(256)
void aggregate_kernel(const unsigned short* __restrict__ F,
                      const int* __restrict__ deg,
                      const int* __restrict__ edge_list,
                      unsigned short* __restrict__ concat) {
    int gw = (blockIdx.x * 256 + threadIdx.x) >> 6;
    if (gw >= N_NODES) return;
    int lane = threadIdx.x & 63;
    int d = deg[gw];
    d = d < CAP ? d : CAP;
    const int* el = edge_list + gw * CAP;
    float acc[8] = {0.f, 0.f, 0.f, 0.f, 0.f, 0.f, 0.f, 0.f};
    int i = 0;
    for (; i + 2 <= d; i += 2) {
        int t0 = el[i], t1 = el[i + 1];
        uint4 p0 = *(const uint4*)(F + (size_t)t0 * D_HID + lane * 8);
        uint4 p1 = *(const uint4*)(F + (size_t)t1 * D_HID + lane * 8);
        fmax_bf16x8(acc, p0);
        fmax_bf16x8(acc, p1);
    }
    if (i < d) {
        uint4 p0 = *(const uint4*)(F + (size_t)el[i] * D_HID + lane * 8);
        fmax_bf16x8(acc, p0);
    }
    unsigned out[4];
    #pragma unroll
    for (int j = 0; j < 4; ++j) {
        unsigned lo = __float_as_uint(acc[2 * j]) >> 16;          // exact: maxima of bf16 values
        unsigned hi = __float_as_uint(acc[2 * j + 1]) & 0xffff0000u;
        out[j] = lo | hi;
    }
    *(uint4*)(concat + (size_t)gw * CAT_DIM + D_IN + lane * 8) = *(uint4*)out;
}

// ================= GEMM2 ===================================================

__global__ __launch_bounds__(256)
void gemm2_kernel(const unsigned short* __restrict__ concat,
                  const unsigned short* __restrict__ WT,
                  float* __restrict__ out) {
    __shared__ char smem[SM64_BYTES];
    gemm_tile64<0, 0>(smem, concat, CAT_DIM, WT, CAT_DIM, nullptr, out, D_OUT,
                      N_NODES, CAT_DIM, blockIdx.x * 64, 0);
}

// ================= host launch =============================================

extern "C" void kernel_launch(void* const* d_in, const int* in_sizes, int n_in,
                              void* d_out, int out_size, void* d_ws, size_t ws_size,
                              hipStream_t stream) {
    const float* X    = (const float*)d_in[0];
    const float* fc_w = (const float*)d_in[1];
    const float* fc_b = (const float*)d_in[2];
    const float* Wm   = (const float*)d_in[3];
    const int*   adj  = (const int*)d_in[4];
    float* outp = (float*)d_out;

    char* ws = (char*)d_ws;
    size_t off = 0;
    auto alloc = [&](size_t bytes) -> void* {
        void* p = ws + off;
        off = (off + bytes + 255) & ~(size_t)255;
        return p;
    };
    unsigned short* concat = (unsigned short*)alloc((size_t)N_NODES * CAT_DIM * 2);
    unsigned short* F      = (unsigned short*)alloc((size_t)N_NODES * D_HID * 2);
    unsigned short* fcwT   = (unsigned short*)alloc((size_t)D_HID * D_IN * 2);
    unsigned short* WT     = (unsigned short*)alloc((size_t)D_OUT * CAT_DIM * 2);
    int* deg       = (int*)alloc((size_t)N_NODES * 4);
    int* edge_list = (int*)alloc((size_t)N_NODES * CAP * 4);
    int* flag      = (int*)alloc(256);

    prep_kernel<<<PREP_TOTAL_BLOCKS, 256, 0, stream>>>(X, fc_w, Wm, adj, concat, fcwT, WT, deg, flag);
    mid_kernel<<<HIST_VB + GEMM1_TILES, 256, 0, stream>>>(adj, flag, deg, edge_list,
                                                          concat, fcwT, fc_b, F);
    aggregate_kernel<<<(N_NODES * 64) / 256, 256, 0, stream>>>(F, deg, edge_list, concat);
    gemm2_kernel<<<GEMM1_MT, 256, 0, stream>>>(concat, WT, outp);
}